// Round 2
// baseline (390.008 us; speedup 1.0000x reference)
//
#include <hip/hip_runtime.h>

#define NN 50000
#define NE 400000
#define NG 64

typedef unsigned int uint32;

// ---------------------------------------------------------------------------
// Linear-GCN collapse (validated round 1, absmax 0.0):
//   x3 = A^3 X (W1W2W3) + (A^2 1)(b1^T W2 W3) + (A 1)(b2^T W3) + 1 b3^T
// with A = D^-1/2 (Adj+I) D^-1/2.
// Round 2: replace fp32 atomic scatter (memory-side RMW, 50MB HBM write/pass)
// with CSR build (2x 400k uint atomics) + 3 pure-gather passes.
// Propagate z = dis .* y:  z'[n] = dis2[n] * (z[n] + sum_{s->n} z[s]).
// ---------------------------------------------------------------------------

// y0 = [x | 1] into A; zero edge counts.
__global__ void k_init(const float* __restrict__ x, uint32* __restrict__ cnt,
                       float* __restrict__ A) {
  int n = blockIdx.x * blockDim.x + threadIdx.x;
  if (n < NN) {
    cnt[n] = 0u;
    float4 v;
    v.x = x[3 * n + 0];
    v.y = x[3 * n + 1];
    v.z = x[3 * n + 2];
    v.w = 1.0f;
    reinterpret_cast<float4*>(A)[n] = v;
  }
}

__global__ void k_count(const int* __restrict__ dst, uint32* __restrict__ cnt) {
  int e = blockIdx.x * blockDim.x + threadIdx.x;
  if (e < NE) atomicAdd(&cnt[dst[e]], 1u);
}

// One block, 1024 threads x 49 elems: exclusive scan of cnt -> off, cursor
// (cursor reuses cnt's storage), dis2 = 1/deg, r = sqrt(deg), and fold
// z0 = y0 * dis in place (A).
__global__ void k_scan(uint32* __restrict__ cnt, uint32* __restrict__ off,
                       float* __restrict__ dis2, float* __restrict__ r,
                       float* __restrict__ A) {
  __shared__ uint32 sums[1024];
  const int CH = 49;
  int t = threadIdx.x;
  int base = t * CH;
  uint32 s = 0;
  for (int i = 0; i < CH; ++i) {
    int idx = base + i;
    if (idx < NN) s += cnt[idx];
  }
  sums[t] = s;
  __syncthreads();
  for (int o = 1; o < 1024; o <<= 1) {
    uint32 v = (t >= o) ? sums[t - o] : 0u;
    __syncthreads();
    sums[t] += v;
    __syncthreads();
  }
  uint32 run = sums[t] - s;  // exclusive base for this chunk
  if (t == 1023) off[NN] = sums[1023];
  for (int i = 0; i < CH; ++i) {
    int idx = base + i;
    if (idx < NN) {
      uint32 c = cnt[idx];
      off[idx] = run;
      cnt[idx] = run;  // becomes scatter cursor
      float deg = (float)(c + 1u);
      float ds = rsqrtf(deg);
      dis2[idx] = 1.0f / deg;
      r[idx] = sqrtf(deg);
      float4 v = reinterpret_cast<const float4*>(A)[idx];
      v.x *= ds; v.y *= ds; v.z *= ds; v.w *= ds;
      reinterpret_cast<float4*>(A)[idx] = v;
      run += c;
    }
  }
}

__global__ void k_scatter(const int* __restrict__ src, const int* __restrict__ dst,
                          uint32* __restrict__ cursor, uint32* __restrict__ csr) {
  int e = blockIdx.x * blockDim.x + threadIdx.x;
  if (e < NE) {
    uint32 p = atomicAdd(&cursor[dst[e]], 1u);
    csr[p] = (uint32)src[e];
  }
}

// 4 lanes per node: z'[n] = dis2[n] * (z[n] + sum_{s in csr[off[n]:off[n+1]]} z[s])
__global__ void k_gather(const uint32* __restrict__ off, const uint32* __restrict__ csr,
                         const float* __restrict__ dis2, const float* __restrict__ zin,
                         float* __restrict__ zout) {
  int tid = blockIdx.x * blockDim.x + threadIdx.x;
  int n = tid >> 2, ln = tid & 3;
  if (n >= NN) return;
  uint32 a = off[n], b = off[n + 1];
  float4 acc = make_float4(0.f, 0.f, 0.f, 0.f);
  for (uint32 i = a + ln; i < b; i += 4) {
    uint32 s = csr[i];
    float4 v = reinterpret_cast<const float4*>(zin)[s];
    acc.x += v.x; acc.y += v.y; acc.z += v.z; acc.w += v.w;
  }
#pragma unroll
  for (int o = 1; o < 4; o <<= 1) {
    acc.x += __shfl_xor(acc.x, o, 64);
    acc.y += __shfl_xor(acc.y, o, 64);
    acc.z += __shfl_xor(acc.z, o, 64);
    acc.w += __shfl_xor(acc.w, o, 64);
  }
  if (ln == 0) {
    float4 zs = reinterpret_cast<const float4*>(zin)[n];
    float w = dis2[n];
    float4 o4;
    o4.x = (acc.x + zs.x) * w;
    o4.y = (acc.y + zs.y) * w;
    o4.z = (acc.z + zs.z) * w;
    o4.w = (acc.w + zs.w) * w;
    reinterpret_cast<float4*>(zout)[n] = o4;
  }
}

// one block, 192 threads: W123 = W1@W2@W3 (3x192), bW23 = b1@W2@W3,
// bW3 = b2@W3; also zero pooled bins.
__global__ void k_weights(const float* __restrict__ W1, const float* __restrict__ b1,
                          const float* __restrict__ W2, const float* __restrict__ b2,
                          const float* __restrict__ W3, float* __restrict__ W123,
                          float* __restrict__ bW23, float* __restrict__ bW3,
                          float* __restrict__ pooled) {
  __shared__ float w12[3 * 48];
  __shared__ float t48[48];
  int t = threadIdx.x;  // 192
  for (int i = t; i < NG * 8; i += 192) pooled[i] = 0.0f;
  if (t < 144) {
    int i = t / 48, k = t % 48;
    float a = 0.f;
    for (int j = 0; j < 24; ++j) a += W1[i * 24 + j] * W2[j * 48 + k];
    w12[t] = a;
  }
  if (t < 48) {
    float a = 0.f;
    for (int j = 0; j < 24; ++j) a += b1[j] * W2[j * 48 + t];
    t48[t] = a;
  }
  __syncthreads();
  float a0 = 0, a1 = 0, a2 = 0, ab = 0, ab3 = 0;
  for (int k = 0; k < 48; ++k) {
    float w3 = W3[k * 192 + t];
    a0 += w12[0 * 48 + k] * w3;
    a1 += w12[1 * 48 + k] * w3;
    a2 += w12[2 * 48 + k] * w3;
    ab += t48[k] * w3;
    ab3 += b2[k] * w3;
  }
  W123[t] = a0;
  W123[192 + t] = a1;
  W123[384 + t] = a2;
  bW23[t] = ab;
  bW3[t] = ab3;
}

static __device__ __forceinline__ float wsum(float v) {
#pragma unroll
  for (int o = 32; o > 0; o >>= 1) v += __shfl_xor(v, o, 64);
  return v;
}

// per-graph sums: y3 = z3*r (cols 0..2 of A), y2.w = C.w*r, y1.w = B.w*r, count
__global__ void k_pool(const int* __restrict__ batch, const float* __restrict__ A,
                       const float* __restrict__ B, const float* __restrict__ C,
                       const float* __restrict__ r, float* __restrict__ pooled) {
  int n = blockIdx.x * blockDim.x + threadIdx.x;
  bool act = n < NN;
  int g = -1;
  float vx = 0, vy = 0, vz = 0, v1 = 0, v2 = 0, c = 0;
  if (act) {
    g = batch[n];
    float rr = r[n];
    float4 a = reinterpret_cast<const float4*>(A)[n];  // z3
    vx = a.x * rr; vy = a.y * rr; vz = a.z * rr;
    v1 = C[4 * n + 3] * rr;  // y2.w = A^2 1
    v2 = B[4 * n + 3] * rr;  // y1.w = A 1
    c = 1.0f;
  }
  int g0 = __shfl(g, 0, 64);
  bool uni = __all(g == g0);
  if (uni) {
    float sx = wsum(vx), sy = wsum(vy), sz = wsum(vz);
    float s1 = wsum(v1), s2 = wsum(v2), sc = wsum(c);
    if ((threadIdx.x & 63) == 0 && g0 >= 0) {
      float* p = pooled + 8 * g0;
      atomicAdd(p + 0, sx); atomicAdd(p + 1, sy); atomicAdd(p + 2, sz);
      atomicAdd(p + 3, s1); atomicAdd(p + 4, s2); atomicAdd(p + 5, sc);
    }
  } else if (act) {
    float* p = pooled + 8 * g;
    atomicAdd(p + 0, vx); atomicAdd(p + 1, vy); atomicAdd(p + 2, vz);
    atomicAdd(p + 3, v1); atomicAdd(p + 4, v2); atomicAdd(p + 5, c);
  }
}

__global__ void k_final(const float* __restrict__ pooled, const float* __restrict__ W123,
                        const float* __restrict__ bW23, const float* __restrict__ bW3,
                        const float* __restrict__ b3, float* __restrict__ out) {
  int g = blockIdx.x;   // 64
  int l = threadIdx.x;  // 192
  const float* p = pooled + 8 * g;
  float ic = 1.0f / fmaxf(p[5], 1.0f);
  float sx = p[0] * ic, sy = p[1] * ic, sz = p[2] * ic;
  float v1 = p[3] * ic, v2 = p[4] * ic;
  out[g * 192 + l] = sx * W123[l] + sy * W123[192 + l] + sz * W123[384 + l] +
                     v1 * bW23[l] + v2 * bW3[l] + b3[l];
}

extern "C" void kernel_launch(void* const* d_in, const int* in_sizes, int n_in,
                              void* d_out, int out_size, void* d_ws, size_t ws_size,
                              hipStream_t stream) {
  const float* x = (const float*)d_in[0];        // [NN,3]
  const int* edges = (const int*)d_in[1];        // [2,NE]
  const int* batch = (const int*)d_in[2];        // [NN]
  const float* W1 = (const float*)d_in[3];
  const float* b1 = (const float*)d_in[4];
  const float* W2 = (const float*)d_in[5];
  const float* b2 = (const float*)d_in[6];
  const float* W3 = (const float*)d_in[7];
  const float* b3 = (const float*)d_in[8];
  float* out = (float*)d_out;

  const int* src = edges;
  const int* dst = edges + NE;

  float* ws = (float*)d_ws;
  uint32* cnt = (uint32*)ws;              // [50000] counts, then cursor
  uint32* off = (uint32*)(ws + 50000);    // [50001]
  float* dis2 = ws + 100004;              // [50000] 1/deg
  float* r = ws + 150004;                 // [50000] sqrt(deg)
  float* A = ws + 200004;                 // [NN*4]  y0 -> z0 -> z3
  float* B = ws + 400004;                 // [NN*4]  z1
  float* C = ws + 600004;                 // [NN*4]  z2
  uint32* csr = (uint32*)(ws + 800004);   // [NE]
  float* pooled = ws + 1200004;           // [NG*8]
  float* W123 = ws + 1200516;             // [3*192]
  float* bW23 = ws + 1201092;             // [192]
  float* bW3 = ws + 1201284;              // [192]

  dim3 bn((NN + 255) / 256), be((NE + 255) / 256), b256(256);
  dim3 bg((NN * 4 + 255) / 256);

  k_init<<<bn, b256, 0, stream>>>(x, cnt, A);
  k_count<<<be, b256, 0, stream>>>(dst, cnt);
  k_scan<<<1, 1024, 0, stream>>>(cnt, off, dis2, r, A);
  k_scatter<<<be, b256, 0, stream>>>(src, dst, cnt, csr);

  k_gather<<<bg, b256, 0, stream>>>(off, csr, dis2, A, B);  // z0 -> z1
  k_gather<<<bg, b256, 0, stream>>>(off, csr, dis2, B, C);  // z1 -> z2
  k_gather<<<bg, b256, 0, stream>>>(off, csr, dis2, C, A);  // z2 -> z3

  k_weights<<<1, 192, 0, stream>>>(W1, b1, W2, b2, W3, W123, bW23, bW3, pooled);
  k_pool<<<bn, b256, 0, stream>>>(batch, A, B, C, r, pooled);
  k_final<<<NG, 192, 0, stream>>>(pooled, W123, bW23, bW3, b3, out);
}

// Round 3
// 103.586 us; speedup vs baseline: 3.7651x; 3.7651x over previous
//
#include <hip/hip_runtime.h>

#define NN 50000
#define NE 400000
#define NG 64
#define NB 196  // ceil(NN/256)

typedef unsigned int uint32;

// ---------------------------------------------------------------------------
// Linear-GCN collapse (validated rounds 1-2, absmax 0.0):
//   x3 = A^3 X (W1W2W3) + (A^2 1)(b1^T W2 W3) + (A 1)(b2^T W3) + 1 b3^T
// with A = D^-1/2 (Adj+I) D^-1/2.
// CSR build (count + 3-kernel parallel scan + cursor scatter) then 3 pure
// gather passes on z = dis .* y:  z'[n] = dis2[n] * (z[n] + sum_{s->n} z[s]).
// Round 3: the single-block scan (304 us, 0.13% occupancy) becomes a
// 3-kernel hierarchical scan (~10 us total).
// ---------------------------------------------------------------------------

// y0 = [x | 1] into A; zero edge counts.
__global__ void k_init(const float* __restrict__ x, uint32* __restrict__ cnt,
                       float* __restrict__ A) {
  int n = blockIdx.x * blockDim.x + threadIdx.x;
  if (n < NN) {
    cnt[n] = 0u;
    float4 v;
    v.x = x[3 * n + 0];
    v.y = x[3 * n + 1];
    v.z = x[3 * n + 2];
    v.w = 1.0f;
    reinterpret_cast<float4*>(A)[n] = v;
  }
}

__global__ void k_count(const int* __restrict__ dst, uint32* __restrict__ cnt) {
  int e = blockIdx.x * blockDim.x + threadIdx.x;
  if (e < NE) atomicAdd(&cnt[dst[e]], 1u);
}

// per-block exclusive scan of cnt chunk -> off (within-block), block sum -> bsum
__global__ void k_scanA(const uint32* __restrict__ cnt, uint32* __restrict__ off,
                        uint32* __restrict__ bsum) {
  __shared__ uint32 sh[256];
  int t = threadIdx.x;
  int i = blockIdx.x * 256 + t;
  uint32 v = (i < NN) ? cnt[i] : 0u;
  sh[t] = v;
  __syncthreads();
  for (int o = 1; o < 256; o <<= 1) {
    uint32 u = (t >= o) ? sh[t - o] : 0u;
    __syncthreads();
    sh[t] += u;
    __syncthreads();
  }
  if (i < NN) off[i] = sh[t] - v;  // exclusive within block
  if (t == 255) bsum[blockIdx.x] = sh[255];
}

// single small block: exclusive scan of the NB block sums in place
__global__ void k_scanB(uint32* __restrict__ bsum) {
  __shared__ uint32 sh[256];
  int t = threadIdx.x;
  uint32 v = (t < NB) ? bsum[t] : 0u;
  sh[t] = v;
  __syncthreads();
  for (int o = 1; o < 256; o <<= 1) {
    uint32 u = (t >= o) ? sh[t - o] : 0u;
    __syncthreads();
    sh[t] += u;
    __syncthreads();
  }
  if (t < NB) bsum[t] = sh[t] - v;
}

// finalize: off += block offset; cursor (in cnt, overwriting count); dis2; r;
// fold z0 = y0 * deg^{-1/2} into A. off[NN] = NE.
__global__ void k_scanC(uint32* __restrict__ cnt, uint32* __restrict__ off,
                        const uint32* __restrict__ bsum, float* __restrict__ dis2,
                        float* __restrict__ r, float* __restrict__ A) {
  int n = blockIdx.x * blockDim.x + threadIdx.x;
  if (n == 0) off[NN] = NE;
  if (n < NN) {
    uint32 c = cnt[n];
    uint32 o = off[n] + bsum[n >> 8];
    off[n] = o;
    cnt[n] = o;  // scatter cursor
    float deg = (float)(c + 1u);
    float ds = rsqrtf(deg);
    dis2[n] = 1.0f / deg;
    r[n] = sqrtf(deg);
    float4 v = reinterpret_cast<const float4*>(A)[n];
    v.x *= ds; v.y *= ds; v.z *= ds; v.w *= ds;
    reinterpret_cast<float4*>(A)[n] = v;
  }
}

__global__ void k_scatter(const int* __restrict__ src, const int* __restrict__ dst,
                          uint32* __restrict__ cursor, uint32* __restrict__ csr) {
  int e = blockIdx.x * blockDim.x + threadIdx.x;
  if (e < NE) {
    uint32 p = atomicAdd(&cursor[dst[e]], 1u);
    csr[p] = (uint32)src[e];
  }
}

// 4 lanes per node: z'[n] = dis2[n] * (z[n] + sum_{s in csr[off[n]:off[n+1]]} z[s])
__global__ void k_gather(const uint32* __restrict__ off, const uint32* __restrict__ csr,
                         const float* __restrict__ dis2, const float* __restrict__ zin,
                         float* __restrict__ zout) {
  int tid = blockIdx.x * blockDim.x + threadIdx.x;
  int n = tid >> 2, ln = tid & 3;
  if (n >= NN) return;
  uint32 a = off[n], b = off[n + 1];
  float4 acc = make_float4(0.f, 0.f, 0.f, 0.f);
  for (uint32 i = a + ln; i < b; i += 4) {
    uint32 s = csr[i];
    float4 v = reinterpret_cast<const float4*>(zin)[s];
    acc.x += v.x; acc.y += v.y; acc.z += v.z; acc.w += v.w;
  }
#pragma unroll
  for (int o = 1; o < 4; o <<= 1) {
    acc.x += __shfl_xor(acc.x, o, 64);
    acc.y += __shfl_xor(acc.y, o, 64);
    acc.z += __shfl_xor(acc.z, o, 64);
    acc.w += __shfl_xor(acc.w, o, 64);
  }
  if (ln == 0) {
    float4 zs = reinterpret_cast<const float4*>(zin)[n];
    float w = dis2[n];
    float4 o4;
    o4.x = (acc.x + zs.x) * w;
    o4.y = (acc.y + zs.y) * w;
    o4.z = (acc.z + zs.z) * w;
    o4.w = (acc.w + zs.w) * w;
    reinterpret_cast<float4*>(zout)[n] = o4;
  }
}

// one block, 192 threads: W123 = W1@W2@W3 (3x192), bW23 = b1@W2@W3,
// bW3 = b2@W3; also zero pooled bins.
__global__ void k_weights(const float* __restrict__ W1, const float* __restrict__ b1,
                          const float* __restrict__ W2, const float* __restrict__ b2,
                          const float* __restrict__ W3, float* __restrict__ W123,
                          float* __restrict__ bW23, float* __restrict__ bW3,
                          float* __restrict__ pooled) {
  __shared__ float w12[3 * 48];
  __shared__ float t48[48];
  int t = threadIdx.x;  // 192
  for (int i = t; i < NG * 8; i += 192) pooled[i] = 0.0f;
  if (t < 144) {
    int i = t / 48, k = t % 48;
    float a = 0.f;
    for (int j = 0; j < 24; ++j) a += W1[i * 24 + j] * W2[j * 48 + k];
    w12[t] = a;
  }
  if (t < 48) {
    float a = 0.f;
    for (int j = 0; j < 24; ++j) a += b1[j] * W2[j * 48 + t];
    t48[t] = a;
  }
  __syncthreads();
  float a0 = 0, a1 = 0, a2 = 0, ab = 0, ab3 = 0;
  for (int k = 0; k < 48; ++k) {
    float w3 = W3[k * 192 + t];
    a0 += w12[0 * 48 + k] * w3;
    a1 += w12[1 * 48 + k] * w3;
    a2 += w12[2 * 48 + k] * w3;
    ab += t48[k] * w3;
    ab3 += b2[k] * w3;
  }
  W123[t] = a0;
  W123[192 + t] = a1;
  W123[384 + t] = a2;
  bW23[t] = ab;
  bW3[t] = ab3;
}

static __device__ __forceinline__ float wsum(float v) {
#pragma unroll
  for (int o = 32; o > 0; o >>= 1) v += __shfl_xor(v, o, 64);
  return v;
}

// per-graph sums: y3 = z3*r (cols 0..2 of A), y2.w = C.w*r, y1.w = B.w*r, count
__global__ void k_pool(const int* __restrict__ batch, const float* __restrict__ A,
                       const float* __restrict__ B, const float* __restrict__ C,
                       const float* __restrict__ r, float* __restrict__ pooled) {
  int n = blockIdx.x * blockDim.x + threadIdx.x;
  bool act = n < NN;
  int g = -1;
  float vx = 0, vy = 0, vz = 0, v1 = 0, v2 = 0, c = 0;
  if (act) {
    g = batch[n];
    float rr = r[n];
    float4 a = reinterpret_cast<const float4*>(A)[n];  // z3
    vx = a.x * rr; vy = a.y * rr; vz = a.z * rr;
    v1 = C[4 * n + 3] * rr;  // y2.w = A^2 1
    v2 = B[4 * n + 3] * rr;  // y1.w = A 1
    c = 1.0f;
  }
  int g0 = __shfl(g, 0, 64);
  bool uni = __all(g == g0);
  if (uni) {
    float sx = wsum(vx), sy = wsum(vy), sz = wsum(vz);
    float s1 = wsum(v1), s2 = wsum(v2), sc = wsum(c);
    if ((threadIdx.x & 63) == 0 && g0 >= 0) {
      float* p = pooled + 8 * g0;
      atomicAdd(p + 0, sx); atomicAdd(p + 1, sy); atomicAdd(p + 2, sz);
      atomicAdd(p + 3, s1); atomicAdd(p + 4, s2); atomicAdd(p + 5, sc);
    }
  } else if (act) {
    float* p = pooled + 8 * g;
    atomicAdd(p + 0, vx); atomicAdd(p + 1, vy); atomicAdd(p + 2, vz);
    atomicAdd(p + 3, v1); atomicAdd(p + 4, v2); atomicAdd(p + 5, c);
  }
}

__global__ void k_final(const float* __restrict__ pooled, const float* __restrict__ W123,
                        const float* __restrict__ bW23, const float* __restrict__ bW3,
                        const float* __restrict__ b3, float* __restrict__ out) {
  int g = blockIdx.x;   // 64
  int l = threadIdx.x;  // 192
  const float* p = pooled + 8 * g;
  float ic = 1.0f / fmaxf(p[5], 1.0f);
  float sx = p[0] * ic, sy = p[1] * ic, sz = p[2] * ic;
  float v1 = p[3] * ic, v2 = p[4] * ic;
  out[g * 192 + l] = sx * W123[l] + sy * W123[192 + l] + sz * W123[384 + l] +
                     v1 * bW23[l] + v2 * bW3[l] + b3[l];
}

extern "C" void kernel_launch(void* const* d_in, const int* in_sizes, int n_in,
                              void* d_out, int out_size, void* d_ws, size_t ws_size,
                              hipStream_t stream) {
  const float* x = (const float*)d_in[0];        // [NN,3]
  const int* edges = (const int*)d_in[1];        // [2,NE]
  const int* batch = (const int*)d_in[2];        // [NN]
  const float* W1 = (const float*)d_in[3];
  const float* b1 = (const float*)d_in[4];
  const float* W2 = (const float*)d_in[5];
  const float* b2 = (const float*)d_in[6];
  const float* W3 = (const float*)d_in[7];
  const float* b3 = (const float*)d_in[8];
  float* out = (float*)d_out;

  const int* src = edges;
  const int* dst = edges + NE;

  float* ws = (float*)d_ws;
  uint32* cnt = (uint32*)ws;              // [50000] counts -> cursor
  uint32* off = (uint32*)(ws + 50000);    // [50001] (padded to 50004)
  uint32* bsum = (uint32*)(ws + 100004);  // [256]
  float* dis2 = ws + 100260;              // [50000] 1/deg
  float* r = ws + 150260;                 // [50000] sqrt(deg)
  float* A = ws + 200260;                 // [NN*4]  y0 -> z0 -> z3
  float* B = ws + 400260;                 // [NN*4]  z1
  float* C = ws + 600260;                 // [NN*4]  z2
  uint32* csr = (uint32*)(ws + 800260);   // [NE]
  float* pooled = ws + 1200260;           // [NG*8]
  float* W123 = ws + 1200772;             // [3*192]
  float* bW23 = ws + 1201348;             // [192]
  float* bW3 = ws + 1201540;              // [192]

  dim3 bn((NN + 255) / 256), be((NE + 255) / 256), b256(256);
  dim3 bg((NN * 4 + 255) / 256);

  k_init<<<bn, b256, 0, stream>>>(x, cnt, A);
  k_count<<<be, b256, 0, stream>>>(dst, cnt);
  k_scanA<<<NB, b256, 0, stream>>>(cnt, off, bsum);
  k_scanB<<<1, b256, 0, stream>>>(bsum);
  k_scanC<<<bn, b256, 0, stream>>>(cnt, off, bsum, dis2, r, A);
  k_scatter<<<be, b256, 0, stream>>>(src, dst, cnt, csr);

  k_gather<<<bg, b256, 0, stream>>>(off, csr, dis2, A, B);  // z0 -> z1
  k_gather<<<bg, b256, 0, stream>>>(off, csr, dis2, B, C);  // z1 -> z2
  k_gather<<<bg, b256, 0, stream>>>(off, csr, dis2, C, A);  // z2 -> z3

  k_weights<<<1, 192, 0, stream>>>(W1, b1, W2, b2, W3, W123, bW23, bW3, pooled);
  k_pool<<<bn, b256, 0, stream>>>(batch, A, B, C, r, pooled);
  k_final<<<NG, 192, 0, stream>>>(pooled, W123, bW23, bW3, b3, out);
}

// Round 4
// 78.697 us; speedup vs baseline: 4.9558x; 1.3163x over previous
//
#include <hip/hip_runtime.h>

#define NN 50000
#define NE 400000
#define NG 64
#define NBK 196   // node buckets of 256 (ceil(NN/256))
#define SB 98     // scatter blocks
#define EPB 4096  // edges per scatter block (SB*EPB >= NE)

typedef unsigned int uint32;
typedef unsigned short uint16;

// ---------------------------------------------------------------------------
// Linear-GCN collapse (validated rounds 1-3, absmax ~2e-6):
//   x3 = A^3 X (W1W2W3) + (A^2 1)(b1^T W2 W3) + (A 1)(b2^T W3) + 1 b3^T
// with A = D^-1/2 (Adj+I) D^-1/2.  Propagate z = dis .* y (width 4).
// Round 4: CSR build via LDS-privatized bucketing — global device-scope
// atomics drop 800k -> ~32k (memory-side RMW was ~18 G/s = ~60 us of 103).
// ---------------------------------------------------------------------------

// y0 = [x | 1] into A; zero bucket histogram.
__global__ void k_init(const float* __restrict__ x, uint32* __restrict__ bhist,
                       float* __restrict__ A) {
  int n = blockIdx.x * blockDim.x + threadIdx.x;
  if (n < NBK) bhist[n] = 0u;
  if (n < NN) {
    float4 v;
    v.x = x[3 * n + 0];
    v.y = x[3 * n + 1];
    v.z = x[3 * n + 2];
    v.w = 1.0f;
    reinterpret_cast<float4*>(A)[n] = v;
  }
}

// per-block LDS histogram of dst>>8, merged globally (64 blocks x 196 bins)
__global__ void __launch_bounds__(256) k_hist(const int* __restrict__ dst,
                                              uint32* __restrict__ bhist) {
  __shared__ uint32 h[NBK];
  int t = threadIdx.x;
  if (t < NBK) h[t] = 0u;
  __syncthreads();
  for (int i = blockIdx.x * 256 + t; i < NE; i += gridDim.x * 256)
    atomicAdd(&h[((uint32)dst[i]) >> 8], 1u);
  __syncthreads();
  if (t < NBK && h[t]) atomicAdd(&bhist[t], h[t]);
}

// 1 block: exclusive scan of bucket sums -> boff; init bucket cursors.
__global__ void k_boff(const uint32* __restrict__ bhist, uint32* __restrict__ boff,
                       uint32* __restrict__ bcur) {
  __shared__ uint32 sh[256];
  int t = threadIdx.x;
  uint32 v = (t < NBK) ? bhist[t] : 0u;
  sh[t] = v;
  __syncthreads();
  for (int o = 1; o < 256; o <<= 1) {
    uint32 u = (t >= o) ? sh[t - o] : 0u;
    __syncthreads();
    sh[t] += u;
    __syncthreads();
  }
  uint32 e = sh[t] - v;
  if (t < NBK) { boff[t] = e; bcur[t] = e; }
  if (t == NBK - 1) boff[NBK] = sh[t];  // == NE
}

// bucket-partition edges: LDS counts, one global reservation per (block,bucket),
// LDS-cursor placement. ebuf entry = src | (dst&255)<<16.
__global__ void __launch_bounds__(256) k_bscat(const int* __restrict__ src,
                                               const int* __restrict__ dst,
                                               uint32* __restrict__ bcur,
                                               uint32* __restrict__ ebuf) {
  __shared__ uint32 cnt[NBK];
  __shared__ uint32 base[NBK];
  int t = threadIdx.x;
  if (t < NBK) cnt[t] = 0u;
  __syncthreads();
  uint32 pk[16];
  uint32 bk[16];
  int e0 = blockIdx.x * EPB + t;
#pragma unroll
  for (int k = 0; k < 16; ++k) {
    int e = e0 + k * 256;
    uint32 b = 0xFFFFFFFFu, p = 0u;
    if (e < NE) {
      uint32 s = (uint32)src[e], d = (uint32)dst[e];
      b = d >> 8;
      p = s | ((d & 255u) << 16);
      atomicAdd(&cnt[b], 1u);
    }
    pk[k] = p;
    bk[k] = b;
  }
  __syncthreads();
  if (t < NBK) {
    uint32 c = cnt[t];
    base[t] = c ? atomicAdd(&bcur[t], c) : 0u;
    cnt[t] = 0u;
  }
  __syncthreads();
#pragma unroll
  for (int k = 0; k < 16; ++k) {
    if (bk[k] != 0xFFFFFFFFu) {
      uint32 slot = base[bk[k]] + atomicAdd(&cnt[bk[k]], 1u);
      ebuf[slot] = pk[k];
    }
  }
}

// one block per bucket: LDS degree count + scan -> off/csr (u16 src ids);
// also deg -> dis2, r, and fold z0 = y0 * deg^{-1/2} into A.
__global__ void __launch_bounds__(256) k_csr(const uint32* __restrict__ boff,
                                             const uint32* __restrict__ ebuf,
                                             uint16* __restrict__ csr,
                                             uint32* __restrict__ off,
                                             float* __restrict__ dis2,
                                             float* __restrict__ r,
                                             float* __restrict__ A) {
  __shared__ uint32 cnt[256];
  __shared__ uint32 scan[256];
  int b = blockIdx.x, t = threadIdx.x;
  uint32 lo = boff[b], hi = boff[b + 1];
  cnt[t] = 0u;
  __syncthreads();
  for (uint32 i = lo + t; i < hi; i += 256)
    atomicAdd(&cnt[ebuf[i] >> 16], 1u);
  __syncthreads();
  uint32 c = cnt[t];
  scan[t] = c;
  __syncthreads();
  for (int o = 1; o < 256; o <<= 1) {
    uint32 u = (t >= o) ? scan[t - o] : 0u;
    __syncthreads();
    scan[t] += u;
    __syncthreads();
  }
  uint32 excl = scan[t] - c;
  cnt[t] = excl;  // becomes local cursor
  int n = b * 256 + t;
  if (n < NN) {
    off[n] = lo + excl;
    float deg = (float)(c + 1u);
    float ds = rsqrtf(deg);
    dis2[n] = 1.0f / deg;
    r[n] = sqrtf(deg);
    float4 v = reinterpret_cast<const float4*>(A)[n];
    v.x *= ds; v.y *= ds; v.z *= ds; v.w *= ds;
    reinterpret_cast<float4*>(A)[n] = v;
  }
  if (b == 0 && t == 0) off[NN] = NE;
  __syncthreads();
  for (uint32 i = lo + t; i < hi; i += 256) {
    uint32 p = ebuf[i];
    uint32 slot = atomicAdd(&cnt[p >> 16], 1u);
    csr[lo + slot] = (uint16)(p & 0xFFFFu);
  }
}

// 4 lanes per node: z'[n] = dis2[n] * (z[n] + sum_{s in csr[off[n]:off[n+1]]} z[s])
__global__ void k_gather(const uint32* __restrict__ off, const uint16* __restrict__ csr,
                         const float* __restrict__ dis2, const float* __restrict__ zin,
                         float* __restrict__ zout) {
  int tid = blockIdx.x * blockDim.x + threadIdx.x;
  int n = tid >> 2, ln = tid & 3;
  if (n >= NN) return;
  uint32 a = off[n], b = off[n + 1];
  float4 acc = make_float4(0.f, 0.f, 0.f, 0.f);
  for (uint32 i = a + ln; i < b; i += 4) {
    uint32 s = csr[i];
    float4 v = reinterpret_cast<const float4*>(zin)[s];
    acc.x += v.x; acc.y += v.y; acc.z += v.z; acc.w += v.w;
  }
#pragma unroll
  for (int o = 1; o < 4; o <<= 1) {
    acc.x += __shfl_xor(acc.x, o, 64);
    acc.y += __shfl_xor(acc.y, o, 64);
    acc.z += __shfl_xor(acc.z, o, 64);
    acc.w += __shfl_xor(acc.w, o, 64);
  }
  if (ln == 0) {
    float4 zs = reinterpret_cast<const float4*>(zin)[n];
    float w = dis2[n];
    float4 o4;
    o4.x = (acc.x + zs.x) * w;
    o4.y = (acc.y + zs.y) * w;
    o4.z = (acc.z + zs.z) * w;
    o4.w = (acc.w + zs.w) * w;
    reinterpret_cast<float4*>(zout)[n] = o4;
  }
}

// one block, 192 threads: W123 = W1@W2@W3 (3x192), bW23 = b1@W2@W3,
// bW3 = b2@W3; also zero pooled bins.
__global__ void k_weights(const float* __restrict__ W1, const float* __restrict__ b1,
                          const float* __restrict__ W2, const float* __restrict__ b2,
                          const float* __restrict__ W3, float* __restrict__ W123,
                          float* __restrict__ bW23, float* __restrict__ bW3,
                          float* __restrict__ pooled) {
  __shared__ float w12[3 * 48];
  __shared__ float t48[48];
  int t = threadIdx.x;  // 192
  for (int i = t; i < NG * 8; i += 192) pooled[i] = 0.0f;
  if (t < 144) {
    int i = t / 48, k = t % 48;
    float a = 0.f;
    for (int j = 0; j < 24; ++j) a += W1[i * 24 + j] * W2[j * 48 + k];
    w12[t] = a;
  }
  if (t < 48) {
    float a = 0.f;
    for (int j = 0; j < 24; ++j) a += b1[j] * W2[j * 48 + t];
    t48[t] = a;
  }
  __syncthreads();
  float a0 = 0, a1 = 0, a2 = 0, ab = 0, ab3 = 0;
  for (int k = 0; k < 48; ++k) {
    float w3 = W3[k * 192 + t];
    a0 += w12[0 * 48 + k] * w3;
    a1 += w12[1 * 48 + k] * w3;
    a2 += w12[2 * 48 + k] * w3;
    ab += t48[k] * w3;
    ab3 += b2[k] * w3;
  }
  W123[t] = a0;
  W123[192 + t] = a1;
  W123[384 + t] = a2;
  bW23[t] = ab;
  bW3[t] = ab3;
}

static __device__ __forceinline__ float wsum(float v) {
#pragma unroll
  for (int o = 32; o > 0; o >>= 1) v += __shfl_xor(v, o, 64);
  return v;
}

// per-graph sums: y3 = z3*r (cols 0..2 of A), y2.w = C.w*r, y1.w = B.w*r, count
__global__ void k_pool(const int* __restrict__ batch, const float* __restrict__ A,
                       const float* __restrict__ B, const float* __restrict__ C,
                       const float* __restrict__ r, float* __restrict__ pooled) {
  int n = blockIdx.x * blockDim.x + threadIdx.x;
  bool act = n < NN;
  int g = -1;
  float vx = 0, vy = 0, vz = 0, v1 = 0, v2 = 0, c = 0;
  if (act) {
    g = batch[n];
    float rr = r[n];
    float4 a = reinterpret_cast<const float4*>(A)[n];  // z3
    vx = a.x * rr; vy = a.y * rr; vz = a.z * rr;
    v1 = C[4 * n + 3] * rr;  // A^2 1
    v2 = B[4 * n + 3] * rr;  // A 1
    c = 1.0f;
  }
  int g0 = __shfl(g, 0, 64);
  bool uni = __all(g == g0);
  if (uni) {
    float sx = wsum(vx), sy = wsum(vy), sz = wsum(vz);
    float s1 = wsum(v1), s2 = wsum(v2), sc = wsum(c);
    if ((threadIdx.x & 63) == 0 && g0 >= 0) {
      float* p = pooled + 8 * g0;
      atomicAdd(p + 0, sx); atomicAdd(p + 1, sy); atomicAdd(p + 2, sz);
      atomicAdd(p + 3, s1); atomicAdd(p + 4, s2); atomicAdd(p + 5, sc);
    }
  } else if (act) {
    float* p = pooled + 8 * g;
    atomicAdd(p + 0, vx); atomicAdd(p + 1, vy); atomicAdd(p + 2, vz);
    atomicAdd(p + 3, v1); atomicAdd(p + 4, v2); atomicAdd(p + 5, c);
  }
}

__global__ void k_final(const float* __restrict__ pooled, const float* __restrict__ W123,
                        const float* __restrict__ bW23, const float* __restrict__ bW3,
                        const float* __restrict__ b3, float* __restrict__ out) {
  int g = blockIdx.x;   // 64
  int l = threadIdx.x;  // 192
  const float* p = pooled + 8 * g;
  float ic = 1.0f / fmaxf(p[5], 1.0f);
  float sx = p[0] * ic, sy = p[1] * ic, sz = p[2] * ic;
  float v1 = p[3] * ic, v2 = p[4] * ic;
  out[g * 192 + l] = sx * W123[l] + sy * W123[192 + l] + sz * W123[384 + l] +
                     v1 * bW23[l] + v2 * bW3[l] + b3[l];
}

extern "C" void kernel_launch(void* const* d_in, const int* in_sizes, int n_in,
                              void* d_out, int out_size, void* d_ws, size_t ws_size,
                              hipStream_t stream) {
  const float* x = (const float*)d_in[0];        // [NN,3]
  const int* edges = (const int*)d_in[1];        // [2,NE]
  const int* batch = (const int*)d_in[2];        // [NN]
  const float* W1 = (const float*)d_in[3];
  const float* b1 = (const float*)d_in[4];
  const float* W2 = (const float*)d_in[5];
  const float* b2 = (const float*)d_in[6];
  const float* W3 = (const float*)d_in[7];
  const float* b3 = (const float*)d_in[8];
  float* out = (float*)d_out;

  const int* src = edges;
  const int* dst = edges + NE;

  float* ws = (float*)d_ws;
  uint32* bhist = (uint32*)ws;              // [256]
  uint32* boff = (uint32*)(ws + 256);       // [197] pad 256
  uint32* bcur = (uint32*)(ws + 512);       // [256]
  uint32* off = (uint32*)(ws + 768);        // [50001] pad 50004
  uint32* ebuf = (uint32*)(ws + 50772);     // [NE]
  uint16* csr = (uint16*)(ws + 450772);     // [NE] u16 = 200000 float words
  float* dis2 = ws + 650772;                // [NN]
  float* r = ws + 700772;                   // [NN]
  float* A = ws + 750772;                   // [NN*4]  y0 -> z0 -> z3
  float* B = ws + 950772;                   // [NN*4]  z1
  float* C = ws + 1150772;                  // [NN*4]  z2
  float* pooled = ws + 1350772;             // [NG*8]
  float* W123 = ws + 1351284;               // [3*192]
  float* bW23 = ws + 1351860;               // [192]
  float* bW3 = ws + 1352052;                // [192]

  dim3 bn((NN + 255) / 256), b256(256);
  dim3 bg((NN * 4 + 255) / 256);

  k_init<<<bn, b256, 0, stream>>>(x, bhist, A);
  k_hist<<<64, b256, 0, stream>>>(dst, bhist);
  k_boff<<<1, b256, 0, stream>>>(bhist, boff, bcur);
  k_bscat<<<SB, b256, 0, stream>>>(src, dst, bcur, ebuf);
  k_csr<<<NBK, b256, 0, stream>>>(boff, ebuf, csr, off, dis2, r, A);

  k_gather<<<bg, b256, 0, stream>>>(off, csr, dis2, A, B);  // z0 -> z1
  k_gather<<<bg, b256, 0, stream>>>(off, csr, dis2, B, C);  // z1 -> z2
  k_gather<<<bg, b256, 0, stream>>>(off, csr, dis2, C, A);  // z2 -> z3

  k_weights<<<1, 192, 0, stream>>>(W1, b1, W2, b2, W3, W123, bW23, bW3, pooled);
  k_pool<<<bn, b256, 0, stream>>>(batch, A, B, C, r, pooled);
  k_final<<<NG, 192, 0, stream>>>(pooled, W123, bW23, bW3, b3, out);
}